// Round 19
// baseline (92.029 us; speedup 1.0000x reference)
//
#include <hip/hip_runtime.h>

// B=4, S=4096, D=64, fp32. Softmax over QUERY axis (per key-column norm):
//   out[b,q,:] = sum_k exp(s[q,k]) * (1/sum_q' exp(s[q',k])) * V[k,:],  s = Q.K^T/8
// v20 = v19 skeleton (full-fp16, K+V staged once, stage->LDS-compute->pin->bar;
// proven: 61.5us total, absmax unchanged) with 4-WAY REUSE GEOMETRY:
// block = 16 waves = qsub(4) x kq(4); q-tile 128; k halved across blocks (kh)
// -> grid 256 (1 block/CU). Per-CU staging 64->32 KB/iter (~1600cy), balancing
// the ~1800cy compute phase. kh partials combine via fp32 atomicAdd (exactly 2
// commutative adds per element = bit-deterministic; out zeroed by memsetAsync).
// v15's failure is now isolated to its skeleton (bf16 hi/lo + lost rotation),
// not this geometry - clean A/B vs v19.

#define B_N 4
#define S_N 4096
#define D_N 64
#define BS_N (B_N * S_N)
#define NCHUNK 128            // 32-row chunks per batch
#define IMG_CH16 4096         // bytes per chunk, fp16 images
#define QSC (0.125f * 1.44269504088896f)

typedef __attribute__((ext_vector_type(4))) float f32x4;
typedef __attribute__((ext_vector_type(2))) float f32x2;
typedef __attribute__((ext_vector_type(8))) _Float16 half8;
typedef unsigned char uchar;

#define MFMAH(A, Bf, C) __builtin_amdgcn_mfma_f32_16x16x32_f16((A), (Bf), (C), 0, 0, 0)

__device__ __forceinline__ void gld16(const void* g, void* l) {
  __builtin_amdgcn_global_load_lds((const __attribute__((address_space(1))) unsigned int*)g,
                                   (__attribute__((address_space(3))) unsigned int*)l, 16, 0, 0);
}

// ---------------------------------------------------------------------------
// prepKQ19: fp32 [B*S][64] -> fp16 fragment-ordered chunk images. (proven)
// Chunk (4KB) = kt(2) x dh(2) x 1KB; lane = ((d0&31)>>3)*16 + (r&15).
// grid 1024: blocks 0..511 = K (scale 1), 512..1023 = Q (scale QSC).
// ---------------------------------------------------------------------------
__global__ __launch_bounds__(256) void sdpa_prepKQ19(const float* __restrict__ K,
                                                     const float* __restrict__ Qm,
                                                     uchar* __restrict__ K16,
                                                     uchar* __restrict__ Q16) {
  const int sel = blockIdx.x >> 9;
  const int c = blockIdx.x & 127;
  const int b = (blockIdx.x >> 7) & 3;
  const int t = threadIdx.x;
  const int r = t >> 3;          // 0..31 row in chunk
  const int d0 = (t & 7) * 8;    // 0..56
  const float* src = (sel ? Qm : K) + ((size_t)(b * S_N + c * 32 + r)) * D_N + d0;
  f32x4 x0 = *(const f32x4*)(src);
  f32x4 x1 = *(const f32x4*)(src + 4);
  const float scale = sel ? QSC : 1.0f;
  x0 *= scale; x1 *= scale;
  half8 hf;
#pragma unroll
  for (int j = 0; j < 4; ++j) { hf[j] = (_Float16)x0[j]; hf[4 + j] = (_Float16)x1[j]; }
  const int kt = r >> 4;
  const int lane = ((d0 & 31) >> 3) * 16 + (r & 15);
  uchar* img = sel ? Q16 : K16;
  *(half8*)(img + ((size_t)(b * NCHUNK + c)) * IMG_CH16 + kt * 2048 + (d0 >> 5) * 1024 + lane * 16) = hf;
}

// ---------------------------------------------------------------------------
// stats16: lPart[qs][b][k] = sum over q-slice qs (16 x 256 q) of exp2(s).
// fp16 (2 MFMAs per 64-dot). grid 1024, block 256; 64 k resident/wave. (proven)
// ---------------------------------------------------------------------------
__global__ __launch_bounds__(256, 4) void sdpa_stats16(const uchar* __restrict__ K16,
                                                       const uchar* __restrict__ Q16,
                                                       float* __restrict__ lPart) {
  const int tid = threadIdx.x, lane = tid & 63, w = tid >> 6;
  const int l15 = lane & 15, g4 = lane >> 4;
  const int xcd = blockIdx.x & 7;
  const int b = xcd >> 1;
  const int r = blockIdx.x >> 3;                  // [0,128)
  const int kt = ((r & 31) << 1) | (xcd & 1);     // [0,64) 64-k tile
  const int qs = ((r >> 5) << 2) | w;             // [0,16) 256-q slice

  half8 kf[4][2];
#pragma unroll
  for (int kg = 0; kg < 4; ++kg) {
    const uchar* kc = K16 + ((size_t)(b * NCHUNK + kt * 2 + (kg >> 1))) * IMG_CH16
                    + (kg & 1) * 2048 + lane * 16;
    kf[kg][0] = *(const half8*)(kc);
    kf[kg][1] = *(const half8*)(kc + 1024);
  }

  float lacc[4][4];
#pragma unroll
  for (int kg = 0; kg < 4; ++kg)
#pragma unroll
    for (int rr = 0; rr < 4; ++rr) lacc[kg][rr] = 0.f;

  const uchar* Qbase = Q16 + ((size_t)(b * NCHUNK + qs * 8)) * IMG_CH16 + lane * 16;

#pragma unroll 1
  for (int it = 0; it < 8; ++it) {
    const uchar* Qc = Qbase + (size_t)it * IMG_CH16;
#pragma unroll
    for (int qt = 0; qt < 2; ++qt) {
      half8 qf0 = *(const half8*)(Qc + qt * 2048);
      half8 qf1 = *(const half8*)(Qc + qt * 2048 + 1024);
#pragma unroll
      for (int kg = 0; kg < 4; ++kg) {
        f32x4 acc = {0.f, 0.f, 0.f, 0.f};
        acc = MFMAH(kf[kg][0], qf0, acc);
        acc = MFMAH(kf[kg][1], qf1, acc);
#pragma unroll
        for (int rr = 0; rr < 4; ++rr)
          lacc[kg][rr] += exp2f(acc[rr]);
      }
    }
  }

#pragma unroll
  for (int off = 1; off < 16; off <<= 1)
#pragma unroll
    for (int kg = 0; kg < 4; ++kg)
#pragma unroll
      for (int rr = 0; rr < 4; ++rr)
        lacc[kg][rr] += __shfl_xor(lacc[kg][rr], off);

  if (l15 == 0) {
#pragma unroll
    for (int kg = 0; kg < 4; ++kg)
#pragma unroll
      for (int rr = 0; rr < 4; ++rr)
        lPart[(size_t)qs * BS_N + b * S_N + kt * 64 + kg * 16 + (g4 << 2) + rr] = lacc[kg][rr];
  }
}

// ---------------------------------------------------------------------------
// prepV8: fp16 permuted VT image (4KB/chunk), rcpl folded (finalize fused).
// Chunk = 4 dt x 1KB; lane = kslotgrp*16 + (d&15). (proven)
// ---------------------------------------------------------------------------
__global__ __launch_bounds__(256) void sdpa_prepV8(const float* __restrict__ V,
                                                   const float* __restrict__ lPart,
                                                   uchar* __restrict__ VT) {
  __shared__ float Vs[32][65];
  __shared__ float rls[32];
  const int c = blockIdx.x & 127;
  const int b = blockIdx.x >> 7;
  const int t = threadIdx.x;
  {
    const int k = t >> 3;
    const int d0 = (t & 7) * 8;
    const float* src = V + ((size_t)(b * S_N + c * 32 + k)) * D_N + d0;
    f32x4 x0 = *(const f32x4*)(src);
    f32x4 x1 = *(const f32x4*)(src + 4);
#pragma unroll
    for (int j = 0; j < 4; ++j) { Vs[k][d0 + j] = x0[j]; Vs[k][d0 + 4 + j] = x1[j]; }
    if (t < 32) {
      float s = 0.f;
      const float* lp = lPart + b * S_N + c * 32 + t;
#pragma unroll
      for (int j = 0; j < 16; ++j) s += lp[(size_t)j * BS_N];
      rls[t] = 1.0f / s;
    }
  }
  __syncthreads();
  const int d = t >> 2;
  const int kg = t & 3;
  half8 hf;
#pragma unroll
  for (int j = 0; j < 8; ++j) {
    const int cc = kg * 8 + j;
    const int k = (((cc >> 2) & 1) << 4) + (((cc >> 3)) << 2) + (cc & 3);
    hf[j] = (_Float16)(Vs[k][d] * rls[k]);
  }
  const int lane = kg * 16 + (d & 15);
  *(half8*)(VT + ((size_t)(b * NCHUNK + c)) * IMG_CH16 + (d >> 4) * 1024 + lane * 16) = hf;
}

// ---------------------------------------------------------------------------
// apply20: grid 256 = b(4, XCD-paired) x qt(32 tiles of 128 q) x kh(2);
// block 1024 = 16 waves = qsub(4, 32 q) x kq(4, 512 k = 16 chunks).
// Per kq-group K+V staged ONCE into dbuf LDS (4 waves x 2 segs each: qsub0/1
// stage K, qsub2/3 stage V); all operands fp16. Per iter: stage(it+1) | SB |
// QK(it) from kslab (8 MFMA) + exp/cvt | PV(it) from vslab (8 MFMA) |
// vmcnt(0) | barrier. Merge 4 kq in-block, then fp32 atomicAdd across kh
// (2 commutative adds/element, out pre-zeroed -> deterministic).
// LDS: 4 kq x 2 par x 8KB = 64KB; Comb (69.6KB) aliases -> sm 69632.
// ---------------------------------------------------------------------------
__global__ __launch_bounds__(1024, 4) void sdpa_apply20(const float* __restrict__ Q,
                                                        const uchar* __restrict__ K16,
                                                        const uchar* __restrict__ VTimg,
                                                        float* __restrict__ Out) {
  __shared__ __attribute__((aligned(16))) uchar sm[69632];  // slabs 64KB; Comb aliases

  const int tid = threadIdx.x, lane = tid & 63, w = tid >> 6;
  const int l15 = lane & 15, g4 = lane >> 4;
  const int qsub = w >> 2, kq = w & 3;
  const int xcd = blockIdx.x & 7;
  const int b = xcd >> 1;
  const int qlow = xcd & 1;
  const int rest = blockIdx.x >> 3;               // 0..31
  const int kh = rest & 1;
  const int qt = ((rest >> 1) << 1) | qlow;       // 0..31, tiles of 128 q

  // Q B-frags (fp16): this wave's 32 q rows (2 qg x 2 d-halves)
  half8 qf[2][2];
#pragma unroll
  for (int qg = 0; qg < 2; ++qg) {
    const int qRow = qt * 128 + qsub * 32 + qg * 16 + l15;
    const float* Qp = Q + ((size_t)(b * S_N + qRow)) * D_N;
    f32x4 x0 = *(const f32x4*)(Qp + g4 * 8);
    f32x4 x1 = *(const f32x4*)(Qp + g4 * 8 + 4);
    f32x4 y0 = *(const f32x4*)(Qp + 32 + g4 * 8);
    f32x4 y1 = *(const f32x4*)(Qp + 36 + g4 * 8);
    x0 *= QSC; x1 *= QSC; y0 *= QSC; y1 *= QSC;
#pragma unroll
    for (int j = 0; j < 4; ++j) {
      qf[qg][0][j] = (_Float16)x0[j]; qf[qg][0][4 + j] = (_Float16)x1[j];
      qf[qg][1][j] = (_Float16)y0[j]; qf[qg][1][4 + j] = (_Float16)y1[j];
    }
  }

  f32x4 accO[2][4];
#pragma unroll
  for (int qg = 0; qg < 2; ++qg)
#pragma unroll
    for (int dt = 0; dt < 4; ++dt) accO[qg][dt] = (f32x4){0.f, 0.f, 0.f, 0.f};

  // this kq-group's chunk stream: chunks kh*64 + kq*16 + it
  const uchar* Kc = K16 + ((size_t)(b * NCHUNK + kh * 64 + kq * 16)) * IMG_CH16 + lane * 16;
  const uchar* Vc = VTimg + ((size_t)(b * NCHUNK + kh * 64 + kq * 16)) * IMG_CH16 + lane * 16;
  uchar* const slab = sm + kq * 16384;    // [par][ K 4KB | V 4KB ]
  const int l16 = lane * 16;

// each wave stages 2 of 8 segs of chunk IT into parity PAR (segs 0-3 K, 4-7 V)
#define STAGE(IT, PAR)                                                         \
  {                                                                            \
    uchar* dstB = slab + (PAR) * 8192;                                         \
    _Pragma("unroll")                                                          \
    for (int si = 0; si < 2; ++si) {                                           \
      const int s = qsub * 2 + si;                                             \
      const uchar* src = (s < 4 ? Kc : Vc) + (size_t)(IT) * IMG_CH16 + (s & 3) * 1024; \
      gld16(src, dstB + s * 1024);                                             \
    }                                                                          \
  }

  // prologue: stage K(0),V(0) -> parity 0
  STAGE(0, 0)
  asm volatile("s_waitcnt vmcnt(0)" ::: "memory");
  __syncthreads();

#pragma unroll 1
  for (int it = 0; it < 16; ++it) {
    const int par = it & 1;
    if (it < 15) STAGE(it + 1, par ^ 1)   // flies under QK+PV
    __builtin_amdgcn_sched_barrier(0);    // stage issues before compute

    const uchar* ks = slab + par * 8192;
    const uchar* vs = ks + 4096;

    // QK(it): A = K frags from LDS, B = Q fp16 regs -> P (exp2, fp16)
    half8 paF[2];
#pragma unroll
    for (int kt = 0; kt < 2; ++kt) {
      half8 kf0 = *(const half8*)(ks + kt * 2048 + l16);
      half8 kf1 = *(const half8*)(ks + kt * 2048 + 1024 + l16);
#pragma unroll
      for (int qg = 0; qg < 2; ++qg) {
        f32x4 acc = {0.f, 0.f, 0.f, 0.f};
        acc = MFMAH(kf0, qf[qg][0], acc);
        acc = MFMAH(kf1, qf[qg][1], acc);
#pragma unroll
        for (int rr = 0; rr < 4; ++rr)
          paF[qg][kt * 4 + rr] = (_Float16)exp2f(acc[rr]);
      }
    }

    // PV(it): A = P regs, B = permuted VT frags from LDS
#pragma unroll
    for (int dt = 0; dt < 4; ++dt) {
      half8 vf = *(const half8*)(vs + dt * 1024 + l16);
#pragma unroll
      for (int qg = 0; qg < 2; ++qg)
        accO[qg][dt] = MFMAH(paF[qg], vf, accO[qg][dt]);
    }

    asm volatile("s_waitcnt vmcnt(0)" ::: "memory");  // stage(it+1) landed
    __syncthreads();                                   // visible to the group
  }

#undef STAGE

  // merge 4 kq partials per qsub strip (two qg phases), then atomicAdd (kh sum)
  float* Comb = (float*)sm;
#pragma unroll
  for (int qg = 0; qg < 2; ++qg) {
    __syncthreads();   // slab reads done / previous phase consumed
    {
      float* CombW = Comb + w * (16 * 68);
#pragma unroll
      for (int dt = 0; dt < 4; ++dt)
#pragma unroll
        for (int r = 0; r < 4; ++r)
          CombW[((g4 << 2) + r) * 68 + dt * 16 + l15] = accO[qg][dt][r];
    }
    __syncthreads();
    {
      const int qs2 = tid >> 8;          // 0..3
      const int row = (tid >> 4) & 15;   // 0..15
      const int c4 = (tid & 15) * 4;     // 0..60
      f32x4 s = {0.f, 0.f, 0.f, 0.f};
#pragma unroll
      for (int kq2 = 0; kq2 < 4; ++kq2)
        s += *(const f32x4*)(Comb + (qs2 * 4 + kq2) * (16 * 68) + row * 68 + c4);
      const int q = qt * 128 + qs2 * 32 + qg * 16 + row;
      float* op = Out + ((size_t)(b * S_N + q)) * D_N + c4;
      atomicAdd(op + 0, s[0]);
      atomicAdd(op + 1, s[1]);
      atomicAdd(op + 2, s[2]);
      atomicAdd(op + 3, s[3]);
    }
  }
}

extern "C" void kernel_launch(void* const* d_in, const int* in_sizes, int n_in,
                              void* d_out, int out_size, void* d_ws, size_t ws_size,
                              hipStream_t stream) {
  (void)in_sizes; (void)n_in;
  const float* Q = (const float*)d_in[0];
  const float* K = (const float*)d_in[1];
  const float* V = (const float*)d_in[2];
  float* out = (float*)d_out;
  uchar* ws = (uchar*)d_ws;

  const size_t img16 = (size_t)B_N * NCHUNK * IMG_CH16;        // 2 MB
  const size_t offK16 = 0;
  const size_t offQ16 = img16;                                 // VT16 aliases after stats
  const size_t offLP = 2 * img16;
  const size_t need = offLP + (size_t)16 * BS_N * 4;           // 5.05 MB (proven)

  if (ws_size < need) return;
  float* lPart = (float*)(ws + offLP);

  hipMemsetAsync(out, 0, (size_t)out_size * sizeof(float), stream);
  sdpa_prepKQ19<<<dim3(1024), dim3(256), 0, stream>>>(K, Q, ws + offK16, ws + offQ16);
  sdpa_stats16<<<dim3(1024), dim3(256), 0, stream>>>(ws + offK16, ws + offQ16, lPart);
  sdpa_prepV8<<<dim3(512), dim3(256), 0, stream>>>(V, lPart, ws + offQ16);
  sdpa_apply20<<<dim3(256), dim3(1024), 0, stream>>>(Q, ws + offK16, ws + offQ16, out);
}

// Round 20
// 76.108 us; speedup vs baseline: 1.2092x; 1.2092x over previous
//
#include <hip/hip_runtime.h>

// B=4, S=4096, D=64, fp32. Softmax over QUERY axis (per key-column norm):
//   out[b,q,:] = sum_k exp(s[q,k]) * (1/sum_q' exp(s[q',k])) * V[k,:],  s = Q.K^T/8
// v21 = v19 (proven 61.5us; apply untouched) with prepKQ FUSED into stats:
//   - stats16c loads raw fp32 K/Q, converts to fp16 in-register (same rounding,
//     same sum order -> bit-identical lPart); the qs==0 wave STORES its K
//     fragment registers as the fragment-ordered K16 image (each chunk written
//     exactly once; consumed only by the later apply launch).
//   - Q16 image deleted (stats and apply both read raw Q).
//   - pipeline: stats16c -> prepV8 -> apply19 (3 launches instead of 4).
// v20's kh/atomics geometry twice-falsified (write-bound, 32MB) - abandoned.

#define B_N 4
#define S_N 4096
#define D_N 64
#define BS_N (B_N * S_N)
#define NCHUNK 128            // 32-row chunks per batch
#define IMG_CH16 4096         // bytes per chunk, fp16 images
#define QSC (0.125f * 1.44269504088896f)

typedef __attribute__((ext_vector_type(4))) float f32x4;
typedef __attribute__((ext_vector_type(2))) float f32x2;
typedef __attribute__((ext_vector_type(8))) _Float16 half8;
typedef unsigned char uchar;

#define MFMAH(A, Bf, C) __builtin_amdgcn_mfma_f32_16x16x32_f16((A), (Bf), (C), 0, 0, 0)

__device__ __forceinline__ void gld16(const void* g, void* l) {
  __builtin_amdgcn_global_load_lds((const __attribute__((address_space(1))) unsigned int*)g,
                                   (__attribute__((address_space(3))) unsigned int*)l, 16, 0, 0);
}

__device__ __forceinline__ half8 cvt8(const f32x4 a, const f32x4 b) {
  half8 h;
#pragma unroll
  for (int j = 0; j < 4; ++j) { h[j] = (_Float16)a[j]; h[4 + j] = (_Float16)b[j]; }
  return h;
}

// ---------------------------------------------------------------------------
// stats16c: lPart[qs][b][k] = sum over q-slice qs (16 x 256 q) of exp2(s).
// Raw fp32 K/Q -> in-register fp16 fragments (2 MFMAs per 64-dot).
// qs==0 wave stores its K fragments as the fragment-ordered K16 image
// (chunk = kt*2+(kg>>1), half kg&1, dh*1024 + lane*16) - written exactly once.
// grid 1024 (16 waves/CU), block 256.
// ---------------------------------------------------------------------------
__global__ __launch_bounds__(256, 4) void sdpa_stats16c(const float* __restrict__ K,
                                                        const float* __restrict__ Qm,
                                                        uchar* __restrict__ K16,
                                                        float* __restrict__ lPart) {
  const int tid = threadIdx.x, lane = tid & 63, w = tid >> 6;
  const int l15 = lane & 15, g4 = lane >> 4;
  const int xcd = blockIdx.x & 7;
  const int b = xcd >> 1;
  const int r = blockIdx.x >> 3;                  // [0,128)
  const int kt = ((r & 31) << 1) | (xcd & 1);     // [0,64) 64-k tile
  const int qs = ((r >> 5) << 2) | w;             // [0,16) 256-q slice

  // K resident from raw fp32, converted once
  half8 kf[4][2];
#pragma unroll
  for (int kg = 0; kg < 4; ++kg) {
    const int row = kt * 64 + kg * 16 + l15;
    const float* Kp = K + ((size_t)(b * S_N + row)) * D_N;
    f32x4 a0 = *(const f32x4*)(Kp + g4 * 8);
    f32x4 a1 = *(const f32x4*)(Kp + g4 * 8 + 4);
    f32x4 b0 = *(const f32x4*)(Kp + 32 + g4 * 8);
    f32x4 b1 = *(const f32x4*)(Kp + 36 + g4 * 8);
    kf[kg][0] = cvt8(a0, a1);
    kf[kg][1] = cvt8(b0, b1);
  }

  // single-writer K16 image store (fragment-ordered, matches apply's reads)
  if (qs == 0) {
#pragma unroll
    for (int kg = 0; kg < 4; ++kg) {
      uchar* base = K16 + ((size_t)(b * NCHUNK + kt * 2 + (kg >> 1))) * IMG_CH16
                  + (kg & 1) * 2048 + lane * 16;
      *(half8*)(base) = kf[kg][0];
      *(half8*)(base + 1024) = kf[kg][1];
    }
  }

  float lacc[4][4];
#pragma unroll
  for (int kg = 0; kg < 4; ++kg)
#pragma unroll
    for (int rr = 0; rr < 4; ++rr) lacc[kg][rr] = 0.f;

  const float* Qb = Qm + ((size_t)(b * S_N + qs * 256)) * D_N;

#pragma unroll 1
  for (int it = 0; it < 8; ++it) {
#pragma unroll
    for (int qt = 0; qt < 2; ++qt) {
      const float* Qp = Qb + ((size_t)(it * 32 + qt * 16 + l15)) * D_N;
      f32x4 a0 = *(const f32x4*)(Qp + g4 * 8);
      f32x4 a1 = *(const f32x4*)(Qp + g4 * 8 + 4);
      f32x4 b0 = *(const f32x4*)(Qp + 32 + g4 * 8);
      f32x4 b1 = *(const f32x4*)(Qp + 36 + g4 * 8);
      a0 *= QSC; a1 *= QSC; b0 *= QSC; b1 *= QSC;
      half8 qf0 = cvt8(a0, a1);
      half8 qf1 = cvt8(b0, b1);
#pragma unroll
      for (int kg = 0; kg < 4; ++kg) {
        f32x4 acc = {0.f, 0.f, 0.f, 0.f};
        acc = MFMAH(kf[kg][0], qf0, acc);
        acc = MFMAH(kf[kg][1], qf1, acc);
#pragma unroll
        for (int rr = 0; rr < 4; ++rr)
          lacc[kg][rr] += exp2f(acc[rr]);
      }
    }
  }

#pragma unroll
  for (int off = 1; off < 16; off <<= 1)
#pragma unroll
    for (int kg = 0; kg < 4; ++kg)
#pragma unroll
      for (int rr = 0; rr < 4; ++rr)
        lacc[kg][rr] += __shfl_xor(lacc[kg][rr], off);

  if (l15 == 0) {
#pragma unroll
    for (int kg = 0; kg < 4; ++kg)
#pragma unroll
      for (int rr = 0; rr < 4; ++rr)
        lPart[(size_t)qs * BS_N + b * S_N + kt * 64 + kg * 16 + (g4 << 2) + rr] = lacc[kg][rr];
  }
}

// ---------------------------------------------------------------------------
// prepV8: fp16 permuted VT image (4KB/chunk), rcpl folded (finalize fused).
// Chunk = 4 dt x 1KB; lane = kslotgrp*16 + (d&15). (proven)
// ---------------------------------------------------------------------------
__global__ __launch_bounds__(256) void sdpa_prepV8(const float* __restrict__ V,
                                                   const float* __restrict__ lPart,
                                                   uchar* __restrict__ VT) {
  __shared__ float Vs[32][65];
  __shared__ float rls[32];
  const int c = blockIdx.x & 127;
  const int b = blockIdx.x >> 7;
  const int t = threadIdx.x;
  {
    const int k = t >> 3;
    const int d0 = (t & 7) * 8;
    const float* src = V + ((size_t)(b * S_N + c * 32 + k)) * D_N + d0;
    f32x4 x0 = *(const f32x4*)(src);
    f32x4 x1 = *(const f32x4*)(src + 4);
#pragma unroll
    for (int j = 0; j < 4; ++j) { Vs[k][d0 + j] = x0[j]; Vs[k][d0 + 4 + j] = x1[j]; }
    if (t < 32) {
      float s = 0.f;
      const float* lp = lPart + b * S_N + c * 32 + t;
#pragma unroll
      for (int j = 0; j < 16; ++j) s += lp[(size_t)j * BS_N];
      rls[t] = 1.0f / s;
    }
  }
  __syncthreads();
  const int d = t >> 2;
  const int kg = t & 3;
  half8 hf;
#pragma unroll
  for (int j = 0; j < 8; ++j) {
    const int cc = kg * 8 + j;
    const int k = (((cc >> 2) & 1) << 4) + (((cc >> 3)) << 2) + (cc & 3);
    hf[j] = (_Float16)(Vs[k][d] * rls[k]);
  }
  const int lane = kg * 16 + (d & 15);
  *(half8*)(VT + ((size_t)(b * NCHUNK + c)) * IMG_CH16 + (d >> 4) * 1024 + lane * 16) = hf;
}

// ---------------------------------------------------------------------------
// apply19 (proven, verbatim): grid 256 = b(4, XCD-paired) x qt(64 tiles of
// 64 q); block 1024 = 16 waves = qsub(2, 32 q) x kq(8, 16 chunks). K+V staged
// once per kq-group into dbuf LDS (qsub1: K(it+1), qsub0: V(it+1)); all fp16.
// Per iter: stage(it+1) | SB | QK(it) from kslab (8 MFMA) + exp/cvt |
// PV(it) from vslab (8 MFMA) | vmcnt(0) | barrier.
// LDS: 8 kq x 2 par x (K 4KB + V 4KB) = 128KB; merge Comb aliases.
// ---------------------------------------------------------------------------
__global__ __launch_bounds__(1024, 4) void sdpa_apply19(const float* __restrict__ Q,
                                                        const uchar* __restrict__ K16,
                                                        const uchar* __restrict__ VTimg,
                                                        float* __restrict__ Out) {
  __shared__ __attribute__((aligned(16))) uchar sm[131072];  // slabs; Comb aliases

  const int tid = threadIdx.x, lane = tid & 63, w = tid >> 6;
  const int l15 = lane & 15, g4 = lane >> 4;
  const int qsub = w >> 3, kq = w & 7;
  const int xcd = blockIdx.x & 7;
  const int b = xcd >> 1;
  const int qt = ((blockIdx.x >> 3) << 1) | (xcd & 1);  // [0,64), tiles of 64 q

  // Q B-frags (fp16): this wave's 32 q rows (2 qg x 2 d-halves)
  half8 qf[2][2];
#pragma unroll
  for (int qg = 0; qg < 2; ++qg) {
    const int qRow = qt * 64 + qsub * 32 + qg * 16 + l15;
    const float* Qp = Q + ((size_t)(b * S_N + qRow)) * D_N;
    f32x4 x0 = *(const f32x4*)(Qp + g4 * 8);
    f32x4 x1 = *(const f32x4*)(Qp + g4 * 8 + 4);
    f32x4 y0 = *(const f32x4*)(Qp + 32 + g4 * 8);
    f32x4 y1 = *(const f32x4*)(Qp + 36 + g4 * 8);
    x0 *= QSC; x1 *= QSC; y0 *= QSC; y1 *= QSC;
    qf[qg][0] = cvt8(x0, x1);
    qf[qg][1] = cvt8(y0, y1);
  }

  f32x4 accO[2][4];
#pragma unroll
  for (int qg = 0; qg < 2; ++qg)
#pragma unroll
    for (int dt = 0; dt < 4; ++dt) accO[qg][dt] = (f32x4){0.f, 0.f, 0.f, 0.f};

  const uchar* Kc = K16 + ((size_t)(b * NCHUNK + kq * 16)) * IMG_CH16 + lane * 16;
  const uchar* Vc = VTimg + ((size_t)(b * NCHUNK + kq * 16)) * IMG_CH16 + lane * 16;
  uchar* const slab = sm + kq * 16384;    // [par][ K 4KB | V 4KB ]
  const int l16 = lane * 16;

// qsub0 stages V chunk IT, qsub1 stages K chunk IT, into parity PAR
#define STAGE(IT, PAR)                                                         \
  {                                                                            \
    uchar* dst = slab + (PAR) * 8192 + (qsub == 0 ? 4096 : 0);                 \
    const uchar* src = (qsub == 0 ? Vc : Kc) + (size_t)(IT) * IMG_CH16;        \
    _Pragma("unroll")                                                          \
    for (int s = 0; s < 4; ++s) gld16(src + s * 1024, dst + s * 1024);         \
  }

  // prologue: stage K(0),V(0) -> parity 0
  STAGE(0, 0)
  asm volatile("s_waitcnt vmcnt(0)" ::: "memory");
  __syncthreads();

#pragma unroll 1
  for (int it = 0; it < 16; ++it) {
    const int par = it & 1;
    if (it < 15) STAGE(it + 1, par ^ 1)   // flies under QK+PV (~600cy)
    __builtin_amdgcn_sched_barrier(0);    // stage issues before compute

    const uchar* ks = slab + par * 8192;
    const uchar* vs = ks + 4096;

    // QK(it): A = K frags from LDS, B = Q fp16 regs -> P (exp2, fp16)
    half8 paF[2];
#pragma unroll
    for (int kt = 0; kt < 2; ++kt) {
      half8 kf0 = *(const half8*)(ks + kt * 2048 + l16);
      half8 kf1 = *(const half8*)(ks + kt * 2048 + 1024 + l16);
#pragma unroll
      for (int qg = 0; qg < 2; ++qg) {
        f32x4 acc = {0.f, 0.f, 0.f, 0.f};
        acc = MFMAH(kf0, qf[qg][0], acc);
        acc = MFMAH(kf1, qf[qg][1], acc);
#pragma unroll
        for (int rr = 0; rr < 4; ++rr)
          paF[qg][kt * 4 + rr] = (_Float16)exp2f(acc[rr]);
      }
    }

    // PV(it): A = P regs, B = permuted VT frags from LDS
#pragma unroll
    for (int dt = 0; dt < 4; ++dt) {
      half8 vf = *(const half8*)(vs + dt * 1024 + l16);
#pragma unroll
      for (int qg = 0; qg < 2; ++qg)
        accO[qg][dt] = MFMAH(paF[qg], vf, accO[qg][dt]);
    }

    asm volatile("s_waitcnt vmcnt(0)" ::: "memory");  // stage(it+1) landed
    __syncthreads();                                   // visible to the pair
  }

#undef STAGE

  // merge 8 kq partials per qsub, two 16-q phases (Comb aliases the slabs)
  float* Comb = (float*)sm;
#pragma unroll
  for (int qg = 0; qg < 2; ++qg) {
    __syncthreads();   // all waves' slab reads done / previous phase consumed
    {
      float* CombW = Comb + w * (16 * 68);
#pragma unroll
      for (int dt = 0; dt < 4; ++dt)
#pragma unroll
        for (int r = 0; r < 4; ++r)
          CombW[((g4 << 2) + r) * 68 + dt * 16 + l15] = accO[qg][dt][r];
    }
    __syncthreads();
    {
      const int qs2 = tid >> 9;            // 0..1
      const int row = (tid >> 5) & 15;     // 0..15
      const int c2 = (tid & 31) * 2;       // 0..62
      f32x2 s = {0.f, 0.f};
#pragma unroll
      for (int kq2 = 0; kq2 < 8; ++kq2)
        s += *(const f32x2*)(Comb + (qs2 * 8 + kq2) * (16 * 68) + row * 68 + c2);
      *(f32x2*)(Out + ((size_t)(b * S_N + qt * 64 + qs2 * 32 + qg * 16 + row)) * D_N + c2) = s;
    }
  }
}

extern "C" void kernel_launch(void* const* d_in, const int* in_sizes, int n_in,
                              void* d_out, int out_size, void* d_ws, size_t ws_size,
                              hipStream_t stream) {
  (void)in_sizes; (void)n_in; (void)out_size;
  const float* Q = (const float*)d_in[0];
  const float* K = (const float*)d_in[1];
  const float* V = (const float*)d_in[2];
  float* out = (float*)d_out;
  uchar* ws = (uchar*)d_ws;

  const size_t img16 = (size_t)B_N * NCHUNK * IMG_CH16;        // 2 MB
  const size_t offK16 = 0;
  const size_t offVT = img16;
  const size_t offLP = 2 * img16;
  const size_t need = offLP + (size_t)16 * BS_N * 4;           // 5.05 MB (proven)

  if (ws_size < need) return;
  float* lPart = (float*)(ws + offLP);

  sdpa_stats16c<<<dim3(1024), dim3(256), 0, stream>>>(K, Q, ws + offK16, lPart);
  sdpa_prepV8<<<dim3(512), dim3(256), 0, stream>>>(V, lPart, ws + offVT);
  sdpa_apply19<<<dim3(256), dim3(1024), 0, stream>>>(Q, ws + offK16, ws + offVT, out);
}

// Round 21
// 64.406 us; speedup vs baseline: 1.4289x; 1.1817x over previous
//
#include <hip/hip_runtime.h>

// B=4, S=4096, D=64, fp32. Softmax over QUERY axis (per key-column norm):
//   out[b,q,:] = sum_k exp(s[q,k]) * (1/sum_q' exp(s[q',k])) * V[k,:],  s = Q.K^T/8
// v22 = v19 pipeline restored (v21's prep-fusion regressed: raw fp32 Q reads
// are uncoalesced + 2x bytes; the fragment-ordered image IS the optimization)
// + stats16d: 128 k resident per wave (kf[8][2]) -> k-tiles halve -> Q-image
// traffic 128->64MB. grid 512, launch_bounds(256,2) (no spill risk, ~115 VGPR).
// Per-column q-sum order unchanged -> bit-identical output.
// apply19 / prepKQ19 / prepV8 verbatim (proven: 61.5us, absmax 0.0009765625).

#define B_N 4
#define S_N 4096
#define D_N 64
#define BS_N (B_N * S_N)
#define NCHUNK 128            // 32-row chunks per batch
#define IMG_CH16 4096         // bytes per chunk, fp16 images
#define QSC (0.125f * 1.44269504088896f)

typedef __attribute__((ext_vector_type(4))) float f32x4;
typedef __attribute__((ext_vector_type(2))) float f32x2;
typedef __attribute__((ext_vector_type(8))) _Float16 half8;
typedef unsigned char uchar;

#define MFMAH(A, Bf, C) __builtin_amdgcn_mfma_f32_16x16x32_f16((A), (Bf), (C), 0, 0, 0)

__device__ __forceinline__ void gld16(const void* g, void* l) {
  __builtin_amdgcn_global_load_lds((const __attribute__((address_space(1))) unsigned int*)g,
                                   (__attribute__((address_space(3))) unsigned int*)l, 16, 0, 0);
}

__device__ __forceinline__ half8 cvt8(const f32x4 a, const f32x4 b) {
  half8 h;
#pragma unroll
  for (int j = 0; j < 4; ++j) { h[j] = (_Float16)a[j]; h[4 + j] = (_Float16)b[j]; }
  return h;
}

// ---------------------------------------------------------------------------
// prepKQ19: fp32 [B*S][64] -> fp16 fragment-ordered chunk images. (proven)
// Chunk (4KB) = kt(2) x dh(2) x 1KB; lane = ((d0&31)>>3)*16 + (r&15).
// grid 1024: blocks 0..511 = K (scale 1), 512..1023 = Q (scale QSC).
// ---------------------------------------------------------------------------
__global__ __launch_bounds__(256) void sdpa_prepKQ19(const float* __restrict__ K,
                                                     const float* __restrict__ Qm,
                                                     uchar* __restrict__ K16,
                                                     uchar* __restrict__ Q16) {
  const int sel = blockIdx.x >> 9;
  const int c = blockIdx.x & 127;
  const int b = (blockIdx.x >> 7) & 3;
  const int t = threadIdx.x;
  const int r = t >> 3;          // 0..31 row in chunk
  const int d0 = (t & 7) * 8;    // 0..56
  const float* src = (sel ? Qm : K) + ((size_t)(b * S_N + c * 32 + r)) * D_N + d0;
  f32x4 x0 = *(const f32x4*)(src);
  f32x4 x1 = *(const f32x4*)(src + 4);
  const float scale = sel ? QSC : 1.0f;
  x0 *= scale; x1 *= scale;
  half8 hf = cvt8(x0, x1);
  const int kt = r >> 4;
  const int lane = ((d0 & 31) >> 3) * 16 + (r & 15);
  uchar* img = sel ? Q16 : K16;
  *(half8*)(img + ((size_t)(b * NCHUNK + c)) * IMG_CH16 + kt * 2048 + (d0 >> 5) * 1024 + lane * 16) = hf;
}

// ---------------------------------------------------------------------------
// stats16d: lPart[qs][b][k] = sum over q-slice qs (16 x 256 q) of exp2(s).
// fp16, 128 k RESIDENT per wave (kf[8][2]) -> Q traffic halved vs stats16.
// grid 512 = xcd(8) x r(64): b=xcd>>1, kt=((r&15)<<1)|(xcd&1) in [0,32)
// (tiles of 128 k), qs=(r>>4)*4+w in [0,16). launch_bounds(256,2).
// ---------------------------------------------------------------------------
__global__ __launch_bounds__(256, 2) void sdpa_stats16d(const uchar* __restrict__ K16,
                                                        const uchar* __restrict__ Q16,
                                                        float* __restrict__ lPart) {
  const int tid = threadIdx.x, lane = tid & 63, w = tid >> 6;
  const int l15 = lane & 15, g4 = lane >> 4;
  const int xcd = blockIdx.x & 7;
  const int b = xcd >> 1;
  const int r = blockIdx.x >> 3;                  // [0,64)
  const int kt = ((r & 15) << 1) | (xcd & 1);     // [0,32) 128-k tile
  const int qs = ((r >> 4) << 2) | w;             // [0,16) 256-q slice

  // K resident: kg 0..7 -> chunk kt*4+(kg>>1), 16-row half kg&1; dh 0..1
  half8 kf[8][2];
#pragma unroll
  for (int kg = 0; kg < 8; ++kg) {
    const uchar* kc = K16 + ((size_t)(b * NCHUNK + kt * 4 + (kg >> 1))) * IMG_CH16
                    + (kg & 1) * 2048 + lane * 16;
    kf[kg][0] = *(const half8*)(kc);
    kf[kg][1] = *(const half8*)(kc + 1024);
  }

  float lacc[8][4];
#pragma unroll
  for (int kg = 0; kg < 8; ++kg)
#pragma unroll
    for (int rr = 0; rr < 4; ++rr) lacc[kg][rr] = 0.f;

  const uchar* Qbase = Q16 + ((size_t)(b * NCHUNK + qs * 8)) * IMG_CH16 + lane * 16;

#pragma unroll 1
  for (int it = 0; it < 8; ++it) {
    const uchar* Qc = Qbase + (size_t)it * IMG_CH16;
#pragma unroll
    for (int qt = 0; qt < 2; ++qt) {
      half8 qf0 = *(const half8*)(Qc + qt * 2048);
      half8 qf1 = *(const half8*)(Qc + qt * 2048 + 1024);
#pragma unroll
      for (int kg = 0; kg < 8; ++kg) {
        f32x4 acc = {0.f, 0.f, 0.f, 0.f};
        acc = MFMAH(kf[kg][0], qf0, acc);
        acc = MFMAH(kf[kg][1], qf1, acc);
#pragma unroll
        for (int rr = 0; rr < 4; ++rr)
          lacc[kg][rr] += exp2f(acc[rr]);
      }
    }
  }

#pragma unroll
  for (int off = 1; off < 16; off <<= 1)
#pragma unroll
    for (int kg = 0; kg < 8; ++kg)
#pragma unroll
      for (int rr = 0; rr < 4; ++rr)
        lacc[kg][rr] += __shfl_xor(lacc[kg][rr], off);

  if (l15 == 0) {
#pragma unroll
    for (int kg = 0; kg < 8; ++kg)
#pragma unroll
      for (int rr = 0; rr < 4; ++rr)
        lPart[(size_t)qs * BS_N + b * S_N + kt * 128 + kg * 16 + (g4 << 2) + rr] = lacc[kg][rr];
  }
}

// ---------------------------------------------------------------------------
// prepV8: fp16 permuted VT image (4KB/chunk), rcpl folded (finalize fused).
// Chunk = 4 dt x 1KB; lane = kslotgrp*16 + (d&15). (proven)
// ---------------------------------------------------------------------------
__global__ __launch_bounds__(256) void sdpa_prepV8(const float* __restrict__ V,
                                                   const float* __restrict__ lPart,
                                                   uchar* __restrict__ VT) {
  __shared__ float Vs[32][65];
  __shared__ float rls[32];
  const int c = blockIdx.x & 127;
  const int b = blockIdx.x >> 7;
  const int t = threadIdx.x;
  {
    const int k = t >> 3;
    const int d0 = (t & 7) * 8;
    const float* src = V + ((size_t)(b * S_N + c * 32 + k)) * D_N + d0;
    f32x4 x0 = *(const f32x4*)(src);
    f32x4 x1 = *(const f32x4*)(src + 4);
#pragma unroll
    for (int j = 0; j < 4; ++j) { Vs[k][d0 + j] = x0[j]; Vs[k][d0 + 4 + j] = x1[j]; }
    if (t < 32) {
      float s = 0.f;
      const float* lp = lPart + b * S_N + c * 32 + t;
#pragma unroll
      for (int j = 0; j < 16; ++j) s += lp[(size_t)j * BS_N];
      rls[t] = 1.0f / s;
    }
  }
  __syncthreads();
  const int d = t >> 2;
  const int kg = t & 3;
  half8 hf;
#pragma unroll
  for (int j = 0; j < 8; ++j) {
    const int cc = kg * 8 + j;
    const int k = (((cc >> 2) & 1) << 4) + (((cc >> 3)) << 2) + (cc & 3);
    hf[j] = (_Float16)(Vs[k][d] * rls[k]);
  }
  const int lane = kg * 16 + (d & 15);
  *(half8*)(VT + ((size_t)(b * NCHUNK + c)) * IMG_CH16 + (d >> 4) * 1024 + lane * 16) = hf;
}

// ---------------------------------------------------------------------------
// apply19 (proven, verbatim): grid 256 = b(4, XCD-paired) x qt(64 tiles of
// 64 q); block 1024 = 16 waves = qsub(2, 32 q) x kq(8, 16 chunks). K+V staged
// once per kq-group into dbuf LDS (qsub1: K(it+1), qsub0: V(it+1)); all fp16.
// Per iter: stage(it+1) | SB | QK(it) from kslab (8 MFMA) + exp/cvt |
// PV(it) from vslab (8 MFMA) | vmcnt(0) | barrier.
// LDS: 8 kq x 2 par x (K 4KB + V 4KB) = 128KB; merge Comb aliases.
// ---------------------------------------------------------------------------
__global__ __launch_bounds__(1024, 4) void sdpa_apply19(const float* __restrict__ Q,
                                                        const uchar* __restrict__ K16,
                                                        const uchar* __restrict__ VTimg,
                                                        float* __restrict__ Out) {
  __shared__ __attribute__((aligned(16))) uchar sm[131072];  // slabs; Comb aliases

  const int tid = threadIdx.x, lane = tid & 63, w = tid >> 6;
  const int l15 = lane & 15, g4 = lane >> 4;
  const int qsub = w >> 3, kq = w & 7;
  const int xcd = blockIdx.x & 7;
  const int b = xcd >> 1;
  const int qt = ((blockIdx.x >> 3) << 1) | (xcd & 1);  // [0,64), tiles of 64 q

  // Q B-frags (fp16): this wave's 32 q rows (2 qg x 2 d-halves)
  half8 qf[2][2];
#pragma unroll
  for (int qg = 0; qg < 2; ++qg) {
    const int qRow = qt * 64 + qsub * 32 + qg * 16 + l15;
    const float* Qp = Q + ((size_t)(b * S_N + qRow)) * D_N;
    f32x4 x0 = *(const f32x4*)(Qp + g4 * 8);
    f32x4 x1 = *(const f32x4*)(Qp + g4 * 8 + 4);
    f32x4 y0 = *(const f32x4*)(Qp + 32 + g4 * 8);
    f32x4 y1 = *(const f32x4*)(Qp + 36 + g4 * 8);
    x0 *= QSC; x1 *= QSC; y0 *= QSC; y1 *= QSC;
    qf[qg][0] = cvt8(x0, x1);
    qf[qg][1] = cvt8(y0, y1);
  }

  f32x4 accO[2][4];
#pragma unroll
  for (int qg = 0; qg < 2; ++qg)
#pragma unroll
    for (int dt = 0; dt < 4; ++dt) accO[qg][dt] = (f32x4){0.f, 0.f, 0.f, 0.f};

  const uchar* Kc = K16 + ((size_t)(b * NCHUNK + kq * 16)) * IMG_CH16 + lane * 16;
  const uchar* Vc = VTimg + ((size_t)(b * NCHUNK + kq * 16)) * IMG_CH16 + lane * 16;
  uchar* const slab = sm + kq * 16384;    // [par][ K 4KB | V 4KB ]
  const int l16 = lane * 16;

// qsub0 stages V chunk IT, qsub1 stages K chunk IT, into parity PAR
#define STAGE(IT, PAR)                                                         \
  {                                                                            \
    uchar* dst = slab + (PAR) * 8192 + (qsub == 0 ? 4096 : 0);                 \
    const uchar* src = (qsub == 0 ? Vc : Kc) + (size_t)(IT) * IMG_CH16;        \
    _Pragma("unroll")                                                          \
    for (int s = 0; s < 4; ++s) gld16(src + s * 1024, dst + s * 1024);         \
  }

  // prologue: stage K(0),V(0) -> parity 0
  STAGE(0, 0)
  asm volatile("s_waitcnt vmcnt(0)" ::: "memory");
  __syncthreads();

#pragma unroll 1
  for (int it = 0; it < 16; ++it) {
    const int par = it & 1;
    if (it < 15) STAGE(it + 1, par ^ 1)   // flies under QK+PV (~600cy)
    __builtin_amdgcn_sched_barrier(0);    // stage issues before compute

    const uchar* ks = slab + par * 8192;
    const uchar* vs = ks + 4096;

    // QK(it): A = K frags from LDS, B = Q fp16 regs -> P (exp2, fp16)
    half8 paF[2];
#pragma unroll
    for (int kt = 0; kt < 2; ++kt) {
      half8 kf0 = *(const half8*)(ks + kt * 2048 + l16);
      half8 kf1 = *(const half8*)(ks + kt * 2048 + 1024 + l16);
#pragma unroll
      for (int qg = 0; qg < 2; ++qg) {
        f32x4 acc = {0.f, 0.f, 0.f, 0.f};
        acc = MFMAH(kf0, qf[qg][0], acc);
        acc = MFMAH(kf1, qf[qg][1], acc);
#pragma unroll
        for (int rr = 0; rr < 4; ++rr)
          paF[qg][kt * 4 + rr] = (_Float16)exp2f(acc[rr]);
      }
    }

    // PV(it): A = P regs, B = permuted VT frags from LDS
#pragma unroll
    for (int dt = 0; dt < 4; ++dt) {
      half8 vf = *(const half8*)(vs + dt * 1024 + l16);
#pragma unroll
      for (int qg = 0; qg < 2; ++qg)
        accO[qg][dt] = MFMAH(paF[qg], vf, accO[qg][dt]);
    }

    asm volatile("s_waitcnt vmcnt(0)" ::: "memory");  // stage(it+1) landed
    __syncthreads();                                   // visible to the pair
  }

#undef STAGE

  // merge 8 kq partials per qsub, two 16-q phases (Comb aliases the slabs)
  float* Comb = (float*)sm;
#pragma unroll
  for (int qg = 0; qg < 2; ++qg) {
    __syncthreads();   // all waves' slab reads done / previous phase consumed
    {
      float* CombW = Comb + w * (16 * 68);
#pragma unroll
      for (int dt = 0; dt < 4; ++dt)
#pragma unroll
        for (int r = 0; r < 4; ++r)
          CombW[((g4 << 2) + r) * 68 + dt * 16 + l15] = accO[qg][dt][r];
    }
    __syncthreads();
    {
      const int qs2 = tid >> 9;            // 0..1
      const int row = (tid >> 5) & 15;     // 0..15
      const int c2 = (tid & 31) * 2;       // 0..62
      f32x2 s = {0.f, 0.f};
#pragma unroll
      for (int kq2 = 0; kq2 < 8; ++kq2)
        s += *(const f32x2*)(Comb + (qs2 * 8 + kq2) * (16 * 68) + row * 68 + c2);
      *(f32x2*)(Out + ((size_t)(b * S_N + qt * 64 + qs2 * 32 + qg * 16 + row)) * D_N + c2) = s;
    }
  }
}

extern "C" void kernel_launch(void* const* d_in, const int* in_sizes, int n_in,
                              void* d_out, int out_size, void* d_ws, size_t ws_size,
                              hipStream_t stream) {
  (void)in_sizes; (void)n_in; (void)out_size;
  const float* Q = (const float*)d_in[0];
  const float* K = (const float*)d_in[1];
  const float* V = (const float*)d_in[2];
  float* out = (float*)d_out;
  uchar* ws = (uchar*)d_ws;

  const size_t img16 = (size_t)B_N * NCHUNK * IMG_CH16;        // 2 MB
  const size_t offK16 = 0;
  const size_t offQ16 = img16;                                 // VT16 aliases after stats
  const size_t offLP = 2 * img16;
  const size_t need = offLP + (size_t)16 * BS_N * 4;           // 5.05 MB (proven)

  if (ws_size < need) return;
  float* lPart = (float*)(ws + offLP);

  sdpa_prepKQ19<<<dim3(1024), dim3(256), 0, stream>>>(K, Q, ws + offK16, ws + offQ16);
  sdpa_stats16d<<<dim3(512), dim3(256), 0, stream>>>(ws + offK16, ws + offQ16, lPart);
  sdpa_prepV8<<<dim3(512), dim3(256), 0, stream>>>(V, lPart, ws + offQ16);
  sdpa_apply19<<<dim3(256), dim3(1024), 0, stream>>>(Q, ws + offK16, ws + offQ16, out);
}

// Round 22
// 63.691 us; speedup vs baseline: 1.4449x; 1.0112x over previous
//
#include <hip/hip_runtime.h>

// B=4, S=4096, D=64, fp32. Softmax over QUERY axis (per key-column norm):
//   out[b,q,:] = sum_k exp(s[q,k]) * (1/sum_q' exp(s[q',k])) * V[k,:],  s = Q.K^T/8
// v23 = v19 (proven best, 61.5us) + stats16e: 128 k resident per wave AND
// full occupancy (q split into 32 slices of 128 -> grid 1024 = 16 waves/CU,
// same as v19's stats16; v22 lost this by halving the grid). Stats traffic
// 160->128MB at unchanged MFMA/exp counts. lPart = 32 partials (2MB, fits ws);
// prepV8 finalize sums 32. apply19 / prepKQ19 verbatim.

#define B_N 4
#define S_N 4096
#define D_N 64
#define BS_N (B_N * S_N)
#define NCHUNK 128            // 32-row chunks per batch
#define IMG_CH16 4096         // bytes per chunk, fp16 images
#define QSC (0.125f * 1.44269504088896f)
#define NSLICE 32             // q-slices in lPart

typedef __attribute__((ext_vector_type(4))) float f32x4;
typedef __attribute__((ext_vector_type(2))) float f32x2;
typedef __attribute__((ext_vector_type(8))) _Float16 half8;
typedef unsigned char uchar;

#define MFMAH(A, Bf, C) __builtin_amdgcn_mfma_f32_16x16x32_f16((A), (Bf), (C), 0, 0, 0)

__device__ __forceinline__ void gld16(const void* g, void* l) {
  __builtin_amdgcn_global_load_lds((const __attribute__((address_space(1))) unsigned int*)g,
                                   (__attribute__((address_space(3))) unsigned int*)l, 16, 0, 0);
}

__device__ __forceinline__ half8 cvt8(const f32x4 a, const f32x4 b) {
  half8 h;
#pragma unroll
  for (int j = 0; j < 4; ++j) { h[j] = (_Float16)a[j]; h[4 + j] = (_Float16)b[j]; }
  return h;
}

// ---------------------------------------------------------------------------
// prepKQ19: fp32 [B*S][64] -> fp16 fragment-ordered chunk images. (proven)
// Chunk (4KB) = kt(2) x dh(2) x 1KB; lane = ((d0&31)>>3)*16 + (r&15).
// grid 1024: blocks 0..511 = K (scale 1), 512..1023 = Q (scale QSC).
// ---------------------------------------------------------------------------
__global__ __launch_bounds__(256) void sdpa_prepKQ19(const float* __restrict__ K,
                                                     const float* __restrict__ Qm,
                                                     uchar* __restrict__ K16,
                                                     uchar* __restrict__ Q16) {
  const int sel = blockIdx.x >> 9;
  const int c = blockIdx.x & 127;
  const int b = (blockIdx.x >> 7) & 3;
  const int t = threadIdx.x;
  const int r = t >> 3;          // 0..31 row in chunk
  const int d0 = (t & 7) * 8;    // 0..56
  const float* src = (sel ? Qm : K) + ((size_t)(b * S_N + c * 32 + r)) * D_N + d0;
  f32x4 x0 = *(const f32x4*)(src);
  f32x4 x1 = *(const f32x4*)(src + 4);
  const float scale = sel ? QSC : 1.0f;
  x0 *= scale; x1 *= scale;
  half8 hf = cvt8(x0, x1);
  const int kt = r >> 4;
  const int lane = ((d0 & 31) >> 3) * 16 + (r & 15);
  uchar* img = sel ? Q16 : K16;
  *(half8*)(img + ((size_t)(b * NCHUNK + c)) * IMG_CH16 + kt * 2048 + (d0 >> 5) * 1024 + lane * 16) = hf;
}

// ---------------------------------------------------------------------------
// stats16e: lPart[qs][b][k] = sum over q-slice qs (32 slices x 128 q) of
// exp2(s). fp16; 128 k RESIDENT per wave (kf[8][2]); grid 1024 = xcd(8) x
// r(128): b=xcd>>1, kt=((r&15)<<1)|(xcd&1) in [0,32) (128-k tiles),
// qs=(r>>4)*4+w in [0,32). 4 blocks/CU -> 16 waves/CU (launch_bounds(256,4)).
// Per wave: 16KB K + 16KB Q (4 chunks) -> stats traffic 160->128MB vs v19.
// ---------------------------------------------------------------------------
__global__ __launch_bounds__(256, 4) void sdpa_stats16e(const uchar* __restrict__ K16,
                                                        const uchar* __restrict__ Q16,
                                                        float* __restrict__ lPart) {
  const int tid = threadIdx.x, lane = tid & 63, w = tid >> 6;
  const int l15 = lane & 15, g4 = lane >> 4;
  const int xcd = blockIdx.x & 7;
  const int b = xcd >> 1;
  const int r = blockIdx.x >> 3;                  // [0,128)
  const int kt = ((r & 15) << 1) | (xcd & 1);     // [0,32) 128-k tile
  const int qs = ((r >> 4) << 2) | w;             // [0,32) 128-q slice

  // K resident: kg 0..7 -> chunk kt*4+(kg>>1), 16-row half kg&1; dh 0..1
  half8 kf[8][2];
#pragma unroll
  for (int kg = 0; kg < 8; ++kg) {
    const uchar* kc = K16 + ((size_t)(b * NCHUNK + kt * 4 + (kg >> 1))) * IMG_CH16
                    + (kg & 1) * 2048 + lane * 16;
    kf[kg][0] = *(const half8*)(kc);
    kf[kg][1] = *(const half8*)(kc + 1024);
  }

  float lacc[8][4];
#pragma unroll
  for (int kg = 0; kg < 8; ++kg)
#pragma unroll
    for (int rr = 0; rr < 4; ++rr) lacc[kg][rr] = 0.f;

  const uchar* Qbase = Q16 + ((size_t)(b * NCHUNK + qs * 4)) * IMG_CH16 + lane * 16;

#pragma unroll 1
  for (int it = 0; it < 4; ++it) {
    const uchar* Qc = Qbase + (size_t)it * IMG_CH16;
#pragma unroll
    for (int qt = 0; qt < 2; ++qt) {
      half8 qf0 = *(const half8*)(Qc + qt * 2048);
      half8 qf1 = *(const half8*)(Qc + qt * 2048 + 1024);
#pragma unroll
      for (int kg = 0; kg < 8; ++kg) {
        f32x4 acc = {0.f, 0.f, 0.f, 0.f};
        acc = MFMAH(kf[kg][0], qf0, acc);
        acc = MFMAH(kf[kg][1], qf1, acc);
#pragma unroll
        for (int rr = 0; rr < 4; ++rr)
          lacc[kg][rr] += exp2f(acc[rr]);
      }
    }
  }

#pragma unroll
  for (int off = 1; off < 16; off <<= 1)
#pragma unroll
    for (int kg = 0; kg < 8; ++kg)
#pragma unroll
      for (int rr = 0; rr < 4; ++rr)
        lacc[kg][rr] += __shfl_xor(lacc[kg][rr], off);

  if (l15 == 0) {
#pragma unroll
    for (int kg = 0; kg < 8; ++kg)
#pragma unroll
      for (int rr = 0; rr < 4; ++rr)
        lPart[(size_t)qs * BS_N + b * S_N + kt * 128 + kg * 16 + (g4 << 2) + rr] = lacc[kg][rr];
  }
}

// ---------------------------------------------------------------------------
// prepV8: fp16 permuted VT image (4KB/chunk), rcpl folded (sums 32 partials).
// Chunk = 4 dt x 1KB; lane = kslotgrp*16 + (d&15). (proven; NSLICE sum)
// ---------------------------------------------------------------------------
__global__ __launch_bounds__(256) void sdpa_prepV8(const float* __restrict__ V,
                                                   const float* __restrict__ lPart,
                                                   uchar* __restrict__ VT) {
  __shared__ float Vs[32][65];
  __shared__ float rls[32];
  const int c = blockIdx.x & 127;
  const int b = blockIdx.x >> 7;
  const int t = threadIdx.x;
  {
    const int k = t >> 3;
    const int d0 = (t & 7) * 8;
    const float* src = V + ((size_t)(b * S_N + c * 32 + k)) * D_N + d0;
    f32x4 x0 = *(const f32x4*)(src);
    f32x4 x1 = *(const f32x4*)(src + 4);
#pragma unroll
    for (int j = 0; j < 4; ++j) { Vs[k][d0 + j] = x0[j]; Vs[k][d0 + 4 + j] = x1[j]; }
    if (t < 32) {
      float s = 0.f;
      const float* lp = lPart + b * S_N + c * 32 + t;
#pragma unroll
      for (int j = 0; j < NSLICE; ++j) s += lp[(size_t)j * BS_N];
      rls[t] = 1.0f / s;
    }
  }
  __syncthreads();
  const int d = t >> 2;
  const int kg = t & 3;
  half8 hf;
#pragma unroll
  for (int j = 0; j < 8; ++j) {
    const int cc = kg * 8 + j;
    const int k = (((cc >> 2) & 1) << 4) + (((cc >> 3)) << 2) + (cc & 3);
    hf[j] = (_Float16)(Vs[k][d] * rls[k]);
  }
  const int lane = kg * 16 + (d & 15);
  *(half8*)(VT + ((size_t)(b * NCHUNK + c)) * IMG_CH16 + (d >> 4) * 1024 + lane * 16) = hf;
}

// ---------------------------------------------------------------------------
// apply19 (proven, verbatim): grid 256 = b(4, XCD-paired) x qt(64 tiles of
// 64 q); block 1024 = 16 waves = qsub(2, 32 q) x kq(8, 16 chunks). K+V staged
// once per kq-group into dbuf LDS (qsub1: K(it+1), qsub0: V(it+1)); all fp16.
// Per iter: stage(it+1) | SB | QK(it) from kslab (8 MFMA) + exp/cvt |
// PV(it) from vslab (8 MFMA) | vmcnt(0) | barrier.
// LDS: 8 kq x 2 par x (K 4KB + V 4KB) = 128KB; merge Comb aliases.
// ---------------------------------------------------------------------------
__global__ __launch_bounds__(1024, 4) void sdpa_apply19(const float* __restrict__ Q,
                                                        const uchar* __restrict__ K16,
                                                        const uchar* __restrict__ VTimg,
                                                        float* __restrict__ Out) {
  __shared__ __attribute__((aligned(16))) uchar sm[131072];  // slabs; Comb aliases

  const int tid = threadIdx.x, lane = tid & 63, w = tid >> 6;
  const int l15 = lane & 15, g4 = lane >> 4;
  const int qsub = w >> 3, kq = w & 7;
  const int xcd = blockIdx.x & 7;
  const int b = xcd >> 1;
  const int qt = ((blockIdx.x >> 3) << 1) | (xcd & 1);  // [0,64), tiles of 64 q

  // Q B-frags (fp16): this wave's 32 q rows (2 qg x 2 d-halves)
  half8 qf[2][2];
#pragma unroll
  for (int qg = 0; qg < 2; ++qg) {
    const int qRow = qt * 64 + qsub * 32 + qg * 16 + l15;
    const float* Qp = Q + ((size_t)(b * S_N + qRow)) * D_N;
    f32x4 x0 = *(const f32x4*)(Qp + g4 * 8);
    f32x4 x1 = *(const f32x4*)(Qp + g4 * 8 + 4);
    f32x4 y0 = *(const f32x4*)(Qp + 32 + g4 * 8);
    f32x4 y1 = *(const f32x4*)(Qp + 36 + g4 * 8);
    x0 *= QSC; x1 *= QSC; y0 *= QSC; y1 *= QSC;
    qf[qg][0] = cvt8(x0, x1);
    qf[qg][1] = cvt8(y0, y1);
  }

  f32x4 accO[2][4];
#pragma unroll
  for (int qg = 0; qg < 2; ++qg)
#pragma unroll
    for (int dt = 0; dt < 4; ++dt) accO[qg][dt] = (f32x4){0.f, 0.f, 0.f, 0.f};

  const uchar* Kc = K16 + ((size_t)(b * NCHUNK + kq * 16)) * IMG_CH16 + lane * 16;
  const uchar* Vc = VTimg + ((size_t)(b * NCHUNK + kq * 16)) * IMG_CH16 + lane * 16;
  uchar* const slab = sm + kq * 16384;    // [par][ K 4KB | V 4KB ]
  const int l16 = lane * 16;

// qsub0 stages V chunk IT, qsub1 stages K chunk IT, into parity PAR
#define STAGE(IT, PAR)                                                         \
  {                                                                            \
    uchar* dst = slab + (PAR) * 8192 + (qsub == 0 ? 4096 : 0);                 \
    const uchar* src = (qsub == 0 ? Vc : Kc) + (size_t)(IT) * IMG_CH16;        \
    _Pragma("unroll")                                                          \
    for (int s = 0; s < 4; ++s) gld16(src + s * 1024, dst + s * 1024);         \
  }

  // prologue: stage K(0),V(0) -> parity 0
  STAGE(0, 0)
  asm volatile("s_waitcnt vmcnt(0)" ::: "memory");
  __syncthreads();

#pragma unroll 1
  for (int it = 0; it < 16; ++it) {
    const int par = it & 1;
    if (it < 15) STAGE(it + 1, par ^ 1)   // flies under QK+PV (~600cy)
    __builtin_amdgcn_sched_barrier(0);    // stage issues before compute

    const uchar* ks = slab + par * 8192;
    const uchar* vs = ks + 4096;

    // QK(it): A = K frags from LDS, B = Q fp16 regs -> P (exp2, fp16)
    half8 paF[2];
#pragma unroll
    for (int kt = 0; kt < 2; ++kt) {
      half8 kf0 = *(const half8*)(ks + kt * 2048 + l16);
      half8 kf1 = *(const half8*)(ks + kt * 2048 + 1024 + l16);
#pragma unroll
      for (int qg = 0; qg < 2; ++qg) {
        f32x4 acc = {0.f, 0.f, 0.f, 0.f};
        acc = MFMAH(kf0, qf[qg][0], acc);
        acc = MFMAH(kf1, qf[qg][1], acc);
#pragma unroll
        for (int rr = 0; rr < 4; ++rr)
          paF[qg][kt * 4 + rr] = (_Float16)exp2f(acc[rr]);
      }
    }

    // PV(it): A = P regs, B = permuted VT frags from LDS
#pragma unroll
    for (int dt = 0; dt < 4; ++dt) {
      half8 vf = *(const half8*)(vs + dt * 1024 + l16);
#pragma unroll
      for (int qg = 0; qg < 2; ++qg)
        accO[qg][dt] = MFMAH(paF[qg], vf, accO[qg][dt]);
    }

    asm volatile("s_waitcnt vmcnt(0)" ::: "memory");  // stage(it+1) landed
    __syncthreads();                                   // visible to the pair
  }

#undef STAGE

  // merge 8 kq partials per qsub, two 16-q phases (Comb aliases the slabs)
  float* Comb = (float*)sm;
#pragma unroll
  for (int qg = 0; qg < 2; ++qg) {
    __syncthreads();   // all waves' slab reads done / previous phase consumed
    {
      float* CombW = Comb + w * (16 * 68);
#pragma unroll
      for (int dt = 0; dt < 4; ++dt)
#pragma unroll
        for (int r = 0; r < 4; ++r)
          CombW[((g4 << 2) + r) * 68 + dt * 16 + l15] = accO[qg][dt][r];
    }
    __syncthreads();
    {
      const int qs2 = tid >> 9;            // 0..1
      const int row = (tid >> 5) & 15;     // 0..15
      const int c2 = (tid & 31) * 2;       // 0..62
      f32x2 s = {0.f, 0.f};
#pragma unroll
      for (int kq2 = 0; kq2 < 8; ++kq2)
        s += *(const f32x2*)(Comb + (qs2 * 8 + kq2) * (16 * 68) + row * 68 + c2);
      *(f32x2*)(Out + ((size_t)(b * S_N + qt * 64 + qs2 * 32 + qg * 16 + row)) * D_N + c2) = s;
    }
  }
}

extern "C" void kernel_launch(void* const* d_in, const int* in_sizes, int n_in,
                              void* d_out, int out_size, void* d_ws, size_t ws_size,
                              hipStream_t stream) {
  (void)in_sizes; (void)n_in; (void)out_size;
  const float* Q = (const float*)d_in[0];
  const float* K = (const float*)d_in[1];
  const float* V = (const float*)d_in[2];
  float* out = (float*)d_out;
  uchar* ws = (uchar*)d_ws;

  const size_t img16 = (size_t)B_N * NCHUNK * IMG_CH16;        // 2 MB
  const size_t offK16 = 0;
  const size_t offQ16 = img16;                                 // VT16 aliases after stats
  const size_t offLP = 2 * img16;
  const size_t need = offLP + (size_t)NSLICE * BS_N * 4;       // 6.05 MB (ws >= 9.05 proven)

  if (ws_size < need) return;
  float* lPart = (float*)(ws + offLP);

  sdpa_prepKQ19<<<dim3(1024), dim3(256), 0, stream>>>(K, Q, ws + offK16, ws + offQ16);
  sdpa_stats16e<<<dim3(1024), dim3(256), 0, stream>>>(ws + offK16, ws + offQ16, lPart);
  sdpa_prepV8<<<dim3(512), dim3(256), 0, stream>>>(V, lPart, ws + offQ16);
  sdpa_apply19<<<dim3(256), dim3(1024), 0, stream>>>(Q, ws + offK16, ws + offQ16, out);
}

// Round 23
// 61.204 us; speedup vs baseline: 1.5036x; 1.0406x over previous
//
#include <hip/hip_runtime.h>

// B=4, S=4096, D=64, fp32. Softmax over QUERY axis (per key-column norm):
//   out[b,q,:] = sum_k exp(s[q,k]) * (1/sum_q' exp(s[q',k])) * V[k,:],  s = Q.K^T/8
// FINAL = v19 verbatim (proven best: 61.5us total, absmax 0.0009765625).
// Two-pass algorithm (column sums -> apply), all-fp16 MFMA operands with fp32
// accumulate, fragment-ordered images, K+V staged once per kq-group via
// global_load_lds double-buffered LDS, permuted-VT in-register P.
// Post-v19 experiments all regressed or neutral: kh-split+atomics (write-bound),
// prep-fusion (uncoalesced), stats k-residency x2 at low occ (latency), at full
// occ (neutral). v19 is the configuration optimum: apply at the per-CU
// global_load_lds delivery ceiling (~14-20 B/cy/CU), stats Q-delivery-bound.

#define B_N 4
#define S_N 4096
#define D_N 64
#define BS_N (B_N * S_N)
#define NCHUNK 128            // 32-row chunks per batch
#define IMG_CH16 4096         // bytes per chunk, fp16 images
#define QSC (0.125f * 1.44269504088896f)

typedef __attribute__((ext_vector_type(4))) float f32x4;
typedef __attribute__((ext_vector_type(2))) float f32x2;
typedef __attribute__((ext_vector_type(8))) _Float16 half8;
typedef unsigned char uchar;

#define MFMAH(A, Bf, C) __builtin_amdgcn_mfma_f32_16x16x32_f16((A), (Bf), (C), 0, 0, 0)

__device__ __forceinline__ void gld16(const void* g, void* l) {
  __builtin_amdgcn_global_load_lds((const __attribute__((address_space(1))) unsigned int*)g,
                                   (__attribute__((address_space(3))) unsigned int*)l, 16, 0, 0);
}

__device__ __forceinline__ half8 cvt8(const f32x4 a, const f32x4 b) {
  half8 h;
#pragma unroll
  for (int j = 0; j < 4; ++j) { h[j] = (_Float16)a[j]; h[4 + j] = (_Float16)b[j]; }
  return h;
}

// ---------------------------------------------------------------------------
// prepKQ19: fp32 [B*S][64] -> fp16 fragment-ordered chunk images.
// Chunk (4KB) = kt(2) x dh(2) x 1KB; lane = ((d0&31)>>3)*16 + (r&15).
// grid 1024: blocks 0..511 = K (scale 1), 512..1023 = Q (scale QSC).
// ---------------------------------------------------------------------------
__global__ __launch_bounds__(256) void sdpa_prepKQ19(const float* __restrict__ K,
                                                     const float* __restrict__ Qm,
                                                     uchar* __restrict__ K16,
                                                     uchar* __restrict__ Q16) {
  const int sel = blockIdx.x >> 9;
  const int c = blockIdx.x & 127;
  const int b = (blockIdx.x >> 7) & 3;
  const int t = threadIdx.x;
  const int r = t >> 3;          // 0..31 row in chunk
  const int d0 = (t & 7) * 8;    // 0..56
  const float* src = (sel ? Qm : K) + ((size_t)(b * S_N + c * 32 + r)) * D_N + d0;
  f32x4 x0 = *(const f32x4*)(src);
  f32x4 x1 = *(const f32x4*)(src + 4);
  const float scale = sel ? QSC : 1.0f;
  x0 *= scale; x1 *= scale;
  half8 hf = cvt8(x0, x1);
  const int kt = r >> 4;
  const int lane = ((d0 & 31) >> 3) * 16 + (r & 15);
  uchar* img = sel ? Q16 : K16;
  *(half8*)(img + ((size_t)(b * NCHUNK + c)) * IMG_CH16 + kt * 2048 + (d0 >> 5) * 1024 + lane * 16) = hf;
}

// ---------------------------------------------------------------------------
// stats16: lPart[qs][b][k] = sum over q-slice qs (16 x 256 q) of exp2(s).
// fp16 (2 MFMAs per 64-dot). grid 1024 (16 waves/CU), block 256;
// 64 k resident/wave; streams 8 Q chunks.
// ---------------------------------------------------------------------------
__global__ __launch_bounds__(256, 4) void sdpa_stats16(const uchar* __restrict__ K16,
                                                       const uchar* __restrict__ Q16,
                                                       float* __restrict__ lPart) {
  const int tid = threadIdx.x, lane = tid & 63, w = tid >> 6;
  const int l15 = lane & 15, g4 = lane >> 4;
  const int xcd = blockIdx.x & 7;
  const int b = xcd >> 1;
  const int r = blockIdx.x >> 3;                  // [0,128)
  const int kt = ((r & 31) << 1) | (xcd & 1);     // [0,64) 64-k tile
  const int qs = ((r >> 5) << 2) | w;             // [0,16) 256-q slice

  half8 kf[4][2];
#pragma unroll
  for (int kg = 0; kg < 4; ++kg) {
    const uchar* kc = K16 + ((size_t)(b * NCHUNK + kt * 2 + (kg >> 1))) * IMG_CH16
                    + (kg & 1) * 2048 + lane * 16;
    kf[kg][0] = *(const half8*)(kc);
    kf[kg][1] = *(const half8*)(kc + 1024);
  }

  float lacc[4][4];
#pragma unroll
  for (int kg = 0; kg < 4; ++kg)
#pragma unroll
    for (int rr = 0; rr < 4; ++rr) lacc[kg][rr] = 0.f;

  const uchar* Qbase = Q16 + ((size_t)(b * NCHUNK + qs * 8)) * IMG_CH16 + lane * 16;

#pragma unroll 1
  for (int it = 0; it < 8; ++it) {
    const uchar* Qc = Qbase + (size_t)it * IMG_CH16;
#pragma unroll
    for (int qt = 0; qt < 2; ++qt) {
      half8 qf0 = *(const half8*)(Qc + qt * 2048);
      half8 qf1 = *(const half8*)(Qc + qt * 2048 + 1024);
#pragma unroll
      for (int kg = 0; kg < 4; ++kg) {
        f32x4 acc = {0.f, 0.f, 0.f, 0.f};
        acc = MFMAH(kf[kg][0], qf0, acc);
        acc = MFMAH(kf[kg][1], qf1, acc);
#pragma unroll
        for (int rr = 0; rr < 4; ++rr)
          lacc[kg][rr] += exp2f(acc[rr]);
      }
    }
  }

#pragma unroll
  for (int off = 1; off < 16; off <<= 1)
#pragma unroll
    for (int kg = 0; kg < 4; ++kg)
#pragma unroll
      for (int rr = 0; rr < 4; ++rr)
        lacc[kg][rr] += __shfl_xor(lacc[kg][rr], off);

  if (l15 == 0) {
#pragma unroll
    for (int kg = 0; kg < 4; ++kg)
#pragma unroll
      for (int rr = 0; rr < 4; ++rr)
        lPart[(size_t)qs * BS_N + b * S_N + kt * 64 + kg * 16 + (g4 << 2) + rr] = lacc[kg][rr];
  }
}

// ---------------------------------------------------------------------------
// prepV8: fp16 permuted VT image (4KB/chunk), rcpl folded (finalize fused).
// Chunk = 4 dt x 1KB; lane = kslotgrp*16 + (d&15).
// ---------------------------------------------------------------------------
__global__ __launch_bounds__(256) void sdpa_prepV8(const float* __restrict__ V,
                                                   const float* __restrict__ lPart,
                                                   uchar* __restrict__ VT) {
  __shared__ float Vs[32][65];
  __shared__ float rls[32];
  const int c = blockIdx.x & 127;
  const int b = blockIdx.x >> 7;
  const int t = threadIdx.x;
  {
    const int k = t >> 3;
    const int d0 = (t & 7) * 8;
    const float* src = V + ((size_t)(b * S_N + c * 32 + k)) * D_N + d0;
    f32x4 x0 = *(const f32x4*)(src);
    f32x4 x1 = *(const f32x4*)(src + 4);
#pragma unroll
    for (int j = 0; j < 4; ++j) { Vs[k][d0 + j] = x0[j]; Vs[k][d0 + 4 + j] = x1[j]; }
    if (t < 32) {
      float s = 0.f;
      const float* lp = lPart + b * S_N + c * 32 + t;
#pragma unroll
      for (int j = 0; j < 16; ++j) s += lp[(size_t)j * BS_N];
      rls[t] = 1.0f / s;
    }
  }
  __syncthreads();
  const int d = t >> 2;
  const int kg = t & 3;
  half8 hf;
#pragma unroll
  for (int j = 0; j < 8; ++j) {
    const int cc = kg * 8 + j;
    const int k = (((cc >> 2) & 1) << 4) + (((cc >> 3)) << 2) + (cc & 3);
    hf[j] = (_Float16)(Vs[k][d] * rls[k]);
  }
  const int lane = kg * 16 + (d & 15);
  *(half8*)(VT + ((size_t)(b * NCHUNK + c)) * IMG_CH16 + (d >> 4) * 1024 + lane * 16) = hf;
}

// ---------------------------------------------------------------------------
// apply19: grid 256 = b(4, XCD-paired) x qt(64 tiles of 64 q); block 1024 =
// 16 waves = qsub(2, 32 q) x kq(8, 16 chunks). K+V staged once per kq-group
// into dbuf LDS (qsub1: K(it+1), qsub0: V(it+1)); all operands fp16.
// Per iter: stage(it+1) | SB | QK(it) from kslab (8 MFMA) + exp/cvt |
// PV(it) from vslab (8 MFMA) | vmcnt(0) | barrier.
// LDS: 8 kq x 2 par x (K 4KB + V 4KB) = 128KB; merge Comb aliases.
// ---------------------------------------------------------------------------
__global__ __launch_bounds__(1024, 4) void sdpa_apply19(const float* __restrict__ Q,
                                                        const uchar* __restrict__ K16,
                                                        const uchar* __restrict__ VTimg,
                                                        float* __restrict__ Out) {
  __shared__ __attribute__((aligned(16))) uchar sm[131072];  // slabs; Comb aliases

  const int tid = threadIdx.x, lane = tid & 63, w = tid >> 6;
  const int l15 = lane & 15, g4 = lane >> 4;
  const int qsub = w >> 3, kq = w & 7;
  const int xcd = blockIdx.x & 7;
  const int b = xcd >> 1;
  const int qt = ((blockIdx.x >> 3) << 1) | (xcd & 1);  // [0,64), tiles of 64 q

  // Q B-frags (fp16): this wave's 32 q rows (2 qg x 2 d-halves)
  half8 qf[2][2];
#pragma unroll
  for (int qg = 0; qg < 2; ++qg) {
    const int qRow = qt * 64 + qsub * 32 + qg * 16 + l15;
    const float* Qp = Q + ((size_t)(b * S_N + qRow)) * D_N;
    f32x4 x0 = *(const f32x4*)(Qp + g4 * 8);
    f32x4 x1 = *(const f32x4*)(Qp + g4 * 8 + 4);
    f32x4 y0 = *(const f32x4*)(Qp + 32 + g4 * 8);
    f32x4 y1 = *(const f32x4*)(Qp + 36 + g4 * 8);
    x0 *= QSC; x1 *= QSC; y0 *= QSC; y1 *= QSC;
    qf[qg][0] = cvt8(x0, x1);
    qf[qg][1] = cvt8(y0, y1);
  }

  f32x4 accO[2][4];
#pragma unroll
  for (int qg = 0; qg < 2; ++qg)
#pragma unroll
    for (int dt = 0; dt < 4; ++dt) accO[qg][dt] = (f32x4){0.f, 0.f, 0.f, 0.f};

  const uchar* Kc = K16 + ((size_t)(b * NCHUNK + kq * 16)) * IMG_CH16 + lane * 16;
  const uchar* Vc = VTimg + ((size_t)(b * NCHUNK + kq * 16)) * IMG_CH16 + lane * 16;
  uchar* const slab = sm + kq * 16384;    // [par][ K 4KB | V 4KB ]
  const int l16 = lane * 16;

// qsub0 stages V chunk IT, qsub1 stages K chunk IT, into parity PAR
#define STAGE(IT, PAR)                                                         \
  {                                                                            \
    uchar* dst = slab + (PAR) * 8192 + (qsub == 0 ? 4096 : 0);                 \
    const uchar* src = (qsub == 0 ? Vc : Kc) + (size_t)(IT) * IMG_CH16;        \
    _Pragma("unroll")                                                          \
    for (int s = 0; s < 4; ++s) gld16(src + s * 1024, dst + s * 1024);         \
  }

  // prologue: stage K(0),V(0) -> parity 0
  STAGE(0, 0)
  asm volatile("s_waitcnt vmcnt(0)" ::: "memory");
  __syncthreads();

#pragma unroll 1
  for (int it = 0; it < 16; ++it) {
    const int par = it & 1;
    if (it < 15) STAGE(it + 1, par ^ 1)   // flies under QK+PV (~600cy)
    __builtin_amdgcn_sched_barrier(0);    // stage issues before compute

    const uchar* ks = slab + par * 8192;
    const uchar* vs = ks + 4096;

    // QK(it): A = K frags from LDS, B = Q fp16 regs -> P (exp2, fp16)
    half8 paF[2];
#pragma unroll
    for (int kt = 0; kt < 2; ++kt) {
      half8 kf0 = *(const half8*)(ks + kt * 2048 + l16);
      half8 kf1 = *(const half8*)(ks + kt * 2048 + 1024 + l16);
#pragma unroll
      for (int qg = 0; qg < 2; ++qg) {
        f32x4 acc = {0.f, 0.f, 0.f, 0.f};
        acc = MFMAH(kf0, qf[qg][0], acc);
        acc = MFMAH(kf1, qf[qg][1], acc);
#pragma unroll
        for (int rr = 0; rr < 4; ++rr)
          paF[qg][kt * 4 + rr] = (_Float16)exp2f(acc[rr]);
      }
    }

    // PV(it): A = P regs, B = permuted VT frags from LDS
#pragma unroll
    for (int dt = 0; dt < 4; ++dt) {
      half8 vf = *(const half8*)(vs + dt * 1024 + l16);
#pragma unroll
      for (int qg = 0; qg < 2; ++qg)
        accO[qg][dt] = MFMAH(paF[qg], vf, accO[qg][dt]);
    }

    asm volatile("s_waitcnt vmcnt(0)" ::: "memory");  // stage(it+1) landed
    __syncthreads();                                   // visible to the pair
  }

#undef STAGE

  // merge 8 kq partials per qsub, two 16-q phases (Comb aliases the slabs)
  float* Comb = (float*)sm;
#pragma unroll
  for (int qg = 0; qg < 2; ++qg) {
    __syncthreads();   // all waves' slab reads done / previous phase consumed
    {
      float* CombW = Comb + w * (16 * 68);
#pragma unroll
      for (int dt = 0; dt < 4; ++dt)
#pragma unroll
        for (int r = 0; r < 4; ++r)
          CombW[((g4 << 2) + r) * 68 + dt * 16 + l15] = accO[qg][dt][r];
    }
    __syncthreads();
    {
      const int qs2 = tid >> 9;            // 0..1
      const int row = (tid >> 5) & 15;     // 0..15
      const int c2 = (tid & 31) * 2;       // 0..62
      f32x2 s = {0.f, 0.f};
#pragma unroll
      for (int kq2 = 0; kq2 < 8; ++kq2)
        s += *(const f32x2*)(Comb + (qs2 * 8 + kq2) * (16 * 68) + row * 68 + c2);
      *(f32x2*)(Out + ((size_t)(b * S_N + qt * 64 + qs2 * 32 + qg * 16 + row)) * D_N + c2) = s;
    }
  }
}

extern "C" void kernel_launch(void* const* d_in, const int* in_sizes, int n_in,
                              void* d_out, int out_size, void* d_ws, size_t ws_size,
                              hipStream_t stream) {
  (void)in_sizes; (void)n_in; (void)out_size;
  const float* Q = (const float*)d_in[0];
  const float* K = (const float*)d_in[1];
  const float* V = (const float*)d_in[2];
  float* out = (float*)d_out;
  uchar* ws = (uchar*)d_ws;

  const size_t img16 = (size_t)B_N * NCHUNK * IMG_CH16;        // 2 MB
  const size_t offK16 = 0;
  const size_t offQ16 = img16;                                 // VT16 aliases after stats
  const size_t offLP = 2 * img16;
  const size_t need = offLP + (size_t)16 * BS_N * 4;           // 5.05 MB (proven)

  if (ws_size < need) return;
  float* lPart = (float*)(ws + offLP);

  sdpa_prepKQ19<<<dim3(1024), dim3(256), 0, stream>>>(K, Q, ws + offK16, ws + offQ16);
  sdpa_stats16<<<dim3(1024), dim3(256), 0, stream>>>(ws + offK16, ws + offQ16, lPart);
  sdpa_prepV8<<<dim3(512), dim3(256), 0, stream>>>(V, lPart, ws + offQ16);
  sdpa_apply19<<<dim3(256), dim3(1024), 0, stream>>>(Q, ws + offK16, ws + offQ16, out);
}